// Round 6
// baseline (186.473 us; speedup 1.0000x reference)
//
#include <hip/hip_runtime.h>

// LIF forward scan: x[T, N] fp32 -> spikes[T, N] fp32, N = B*C*H*W = 4,194,304.
// Per-column recurrence (exact reference arithmetic, absmax 0.0 R1/R3/R4/R5):
//   v = v + (x_t - v) * 0.5   (TAU=2; *0.5 exact -> FMA-contraction-safe)
//   s = (v - 1.0 >= 0) ? 1 : 0
//   v = (1 - s) * v
//
// R6 vs R5 (182.4 us, 5.89 TB/s = 93.6% of 6.29 TB/s copy ceiling):
//  - 8 float4 columns per thread (i + k*256, k=0..7): per-timestep wave
//    read run = 8 KB contiguous, write run = 8 KB contiguous.
//  - grid = 512 blocks = 2048 waves = 2 blocks/CU (2 waves/SIMD). Latency
//    math: need ~2.3 KB in flight/SIMD; we keep ~32 KB (8 loads + 8 stores
//    per wave x 2 waves) -> low occupancy is fine.
//  - one-timestep register prefetch (double-buffer); all per-column loops
//    fully unrolled so array indices are compile-time (no scratch).
//  - nontemporal on both streams (touch-once, 1 GB >> 256 MB L3).

typedef float f32x4 __attribute__((ext_vector_type(4)));

#define NCOL 8

// v updated in place; returns spike vector.
__device__ __forceinline__ f32x4 lif_step(f32x4& v, const f32x4 xt) {
  f32x4 s;
  v.x = v.x + (xt.x - v.x) * 0.5f;
  v.y = v.y + (xt.y - v.y) * 0.5f;
  v.z = v.z + (xt.z - v.z) * 0.5f;
  v.w = v.w + (xt.w - v.w) * 0.5f;
  s.x = (v.x - 1.0f >= 0.0f) ? 1.0f : 0.0f;
  s.y = (v.y - 1.0f >= 0.0f) ? 1.0f : 0.0f;
  s.z = (v.z - 1.0f >= 0.0f) ? 1.0f : 0.0f;
  s.w = (v.w - 1.0f >= 0.0f) ? 1.0f : 0.0f;
  v.x *= (1.0f - s.x);
  v.y *= (1.0f - s.y);
  v.z *= (1.0f - s.z);
  v.w *= (1.0f - s.w);
  return s;
}

__global__ __launch_bounds__(256) void lif_fwd_kernel(
    const f32x4* __restrict__ x, f32x4* __restrict__ out,
    int n4, int T) {
  // 8 block-strided float4 columns per thread: wave-contiguous 8 KB runs.
  const int i = blockIdx.x * (256 * NCOL) + threadIdx.x;

  const f32x4* __restrict__ px = x + i;
  f32x4* __restrict__ po = out + i;

  f32x4 v[NCOL];
  f32x4 a[NCOL];

  #pragma unroll
  for (int k = 0; k < NCOL; ++k) v[k] = (f32x4){0.f, 0.f, 0.f, 0.f};

  // prologue: prefetch t=0 (8 loads, 8 KB wave run)
  #pragma unroll
  for (int k = 0; k < NCOL; ++k)
    a[k] = __builtin_nontemporal_load(px + k * 256);

  for (int t = 0; t < T - 1; ++t) {
    // issue t+1's loads before t's compute/store (register double-buffer)
    const size_t offn = (size_t)(t + 1) * n4;
    f32x4 na[NCOL];
    #pragma unroll
    for (int k = 0; k < NCOL; ++k)
      na[k] = __builtin_nontemporal_load(px + offn + k * 256);

    // compute 8 lif steps (results reuse the a registers)
    #pragma unroll
    for (int k = 0; k < NCOL; ++k)
      a[k] = lif_step(v[k], a[k]);

    // 8 back-to-back stores (8 KB wave run)
    const size_t offo = (size_t)t * n4;
    #pragma unroll
    for (int k = 0; k < NCOL; ++k)
      __builtin_nontemporal_store(a[k], po + offo + k * 256);

    #pragma unroll
    for (int k = 0; k < NCOL; ++k) a[k] = na[k];
  }

  // epilogue: last timestep
  {
    #pragma unroll
    for (int k = 0; k < NCOL; ++k)
      a[k] = lif_step(v[k], a[k]);
    const size_t offo = (size_t)(T - 1) * n4;
    #pragma unroll
    for (int k = 0; k < NCOL; ++k)
      __builtin_nontemporal_store(a[k], po + offo + k * 256);
  }
}

extern "C" void kernel_launch(void* const* d_in, const int* in_sizes, int n_in,
                              void* d_out, int out_size, void* d_ws, size_t ws_size,
                              hipStream_t stream) {
  const float* x = (const float*)d_in[0];
  float* out = (float*)d_out;

  const int T = 32;
  const int total = in_sizes[0];   // T * N
  const int N = total / T;         // 4,194,304
  const int n4 = N / 4;            // 1,048,576 float4 columns

  const int block = 256;
  const int grid = n4 / (block * NCOL);  // 512 blocks, 8 float4 per thread

  lif_fwd_kernel<<<grid, block, 0, stream>>>(
      (const f32x4*)x, (f32x4*)out, n4, T);
}

// Round 7
// 182.616 us; speedup vs baseline: 1.0211x; 1.0211x over previous
//
#include <hip/hip_runtime.h>

// LIF forward scan: x[T, N] fp32 -> spikes[T, N] fp32, N = B*C*H*W = 4,194,304.
// Per-column recurrence (exact reference arithmetic, absmax 0.0 every round):
//   v = v + (x_t - v) * 0.5   (TAU=2; *0.5 exact -> FMA-contraction-safe)
//   s = (v - 1.0 >= 0) ? 1 : 0
//   v = (1 - s) * v
//
// R7 = revert to R5 (best: 182.4 us, 5.89 TB/s = 93.6% of 6.29 TB/s copy
// ceiling). R6's 8-col/512-block variant regressed to 186.5 us -> the
// run-length ladder (1->2->4 KB helped, 8 KB hurt) peaks at 4 cols/thread.
//
//  - 4 float4 columns per thread (i, i+256, i+512, i+768): each wave's
//    per-timestep read run = 4 KB contiguous, write run = 4 KB contiguous.
//  - grid = 1024 blocks = 4096 waves (4 blocks/CU) -> scheduling slack.
//  - one-timestep register prefetch -> 8 KB in flight per wave.
//  - nontemporal on both streams (touch-once, 1 GB >> 256 MB L3).

typedef float f32x4 __attribute__((ext_vector_type(4)));

// v updated in place; returns spike vector.
__device__ __forceinline__ f32x4 lif_step(f32x4& v, const f32x4 xt) {
  f32x4 s;
  v.x = v.x + (xt.x - v.x) * 0.5f;
  v.y = v.y + (xt.y - v.y) * 0.5f;
  v.z = v.z + (xt.z - v.z) * 0.5f;
  v.w = v.w + (xt.w - v.w) * 0.5f;
  s.x = (v.x - 1.0f >= 0.0f) ? 1.0f : 0.0f;
  s.y = (v.y - 1.0f >= 0.0f) ? 1.0f : 0.0f;
  s.z = (v.z - 1.0f >= 0.0f) ? 1.0f : 0.0f;
  s.w = (v.w - 1.0f >= 0.0f) ? 1.0f : 0.0f;
  v.x *= (1.0f - s.x);
  v.y *= (1.0f - s.y);
  v.z *= (1.0f - s.z);
  v.w *= (1.0f - s.w);
  return s;
}

__global__ __launch_bounds__(256) void lif_fwd_kernel(
    const f32x4* __restrict__ x, f32x4* __restrict__ out,
    int n4, int T) {
  // 4 block-strided float4 columns per thread: wave-contiguous 4 KB runs.
  const int i = blockIdx.x * 1024 + threadIdx.x;

  const f32x4* __restrict__ px = x + i;
  f32x4* __restrict__ po = out + i;

  f32x4 v0 = (f32x4){0.f, 0.f, 0.f, 0.f};
  f32x4 v1 = (f32x4){0.f, 0.f, 0.f, 0.f};
  f32x4 v2 = (f32x4){0.f, 0.f, 0.f, 0.f};
  f32x4 v3 = (f32x4){0.f, 0.f, 0.f, 0.f};

  // prologue: prefetch t=0 (4 loads, 4 KB wave run)
  f32x4 a0 = __builtin_nontemporal_load(px);
  f32x4 a1 = __builtin_nontemporal_load(px + 256);
  f32x4 a2 = __builtin_nontemporal_load(px + 512);
  f32x4 a3 = __builtin_nontemporal_load(px + 768);

  #pragma unroll 2
  for (int t = 0; t < T - 1; ++t) {
    // issue t+1's loads before t's compute/store (register double-buffer)
    const size_t offn = (size_t)(t + 1) * n4;
    f32x4 na0 = __builtin_nontemporal_load(px + offn);
    f32x4 na1 = __builtin_nontemporal_load(px + offn + 256);
    f32x4 na2 = __builtin_nontemporal_load(px + offn + 512);
    f32x4 na3 = __builtin_nontemporal_load(px + offn + 768);

    // compute 4 lif steps (results reuse the a registers)
    a0 = lif_step(v0, a0);
    a1 = lif_step(v1, a1);
    a2 = lif_step(v2, a2);
    a3 = lif_step(v3, a3);

    // 4 back-to-back stores (4 KB wave run)
    const size_t offo = (size_t)t * n4;
    __builtin_nontemporal_store(a0, po + offo);
    __builtin_nontemporal_store(a1, po + offo + 256);
    __builtin_nontemporal_store(a2, po + offo + 512);
    __builtin_nontemporal_store(a3, po + offo + 768);

    a0 = na0; a1 = na1; a2 = na2; a3 = na3;
  }

  // epilogue: last timestep
  {
    a0 = lif_step(v0, a0);
    a1 = lif_step(v1, a1);
    a2 = lif_step(v2, a2);
    a3 = lif_step(v3, a3);
    const size_t offo = (size_t)(T - 1) * n4;
    __builtin_nontemporal_store(a0, po + offo);
    __builtin_nontemporal_store(a1, po + offo + 256);
    __builtin_nontemporal_store(a2, po + offo + 512);
    __builtin_nontemporal_store(a3, po + offo + 768);
  }
}

extern "C" void kernel_launch(void* const* d_in, const int* in_sizes, int n_in,
                              void* d_out, int out_size, void* d_ws, size_t ws_size,
                              hipStream_t stream) {
  const float* x = (const float*)d_in[0];
  float* out = (float*)d_out;

  const int T = 32;
  const int total = in_sizes[0];   // T * N
  const int N = total / T;         // 4,194,304
  const int n4 = N / 4;            // 1,048,576 float4 columns

  const int block = 256;
  const int grid = n4 / (block * 4);  // 1024 blocks, 4 float4 per thread

  lif_fwd_kernel<<<grid, block, 0, stream>>>(
      (const f32x4*)x, (f32x4*)out, n4, T);
}